// Round 17
// baseline (773.551 us; speedup 1.0000x reference)
//
#include <hip/hip_runtime.h>

typedef __attribute__((ext_vector_type(8))) short short8;
typedef __attribute__((ext_vector_type(4))) float f32x4;
typedef __attribute__((ext_vector_type(4))) unsigned short us4v;
typedef unsigned short ushort_t;
typedef unsigned int uint_t;

#define BB 4
#define T_ 1024
#define T2 2048
#define DD 256
#define DIN 512
#define NMARK 64
#define LNEPS 1e-5f
#define KDIV (-0.035977892078032f)
#define SEGL 8

__device__ __forceinline__ ushort_t f2bf(float f) {
  unsigned int u = __float_as_uint(f);
  unsigned int r = (u + 0x7fffu + ((u >> 16) & 1u)) >> 16;
  return (ushort_t)r;
}
__device__ __forceinline__ float bf2f(ushort_t v) {
  return __uint_as_float(((uint_t)v) << 16);
}
__device__ __forceinline__ uint_t pack2(float a, float b) {
  return (uint_t)f2bf(a) | ((uint_t)f2bf(b) << 16);
}
__device__ __forceinline__ uint_t cvtpk(float lo, float hi) {
  uint_t r;
  asm("v_cvt_pk_bf16_f32 %0, %1, %2" : "=v"(r) : "v"(lo), "v"(hi));
  return r;
}

typedef const __attribute__((address_space(1))) unsigned int* as1cu32;
typedef __attribute__((address_space(3))) unsigned int* as3u32;
__device__ __forceinline__ void async_copy16(const void* g, void* l) {
  __builtin_amdgcn_global_load_lds((as1cu32)g, (as3u32)l, 16, 0, 0);
}

// ---------- init: type/time embeddings -> Xh (bf16), Cur = 0 ----------
__global__ __launch_bounds__(256) void k_init(const float* __restrict__ ev,
                                              const float* __restrict__ tm,
                                              const float* __restrict__ Wt,
                                              const float* __restrict__ bt,
                                              ushort_t* __restrict__ Xh,
                                              float* __restrict__ Cur) {
  const int btq = blockIdx.x;
  const int b = btq >> 10;
  const int t = btq & 1023;
  const int d = threadIdx.x;
  __shared__ float evs[NMARK];
  if (d < NMARK) evs[d] = ev[(size_t)btq * NMARK + d];
  __syncthreads();
  float s = bt[d];
#pragma unroll
  for (int m = 0; m < NMARK; ++m) s += evs[m] * Wt[m * DD + d];
  const float te_type = tanhf(s);
  const float tv = tm[btq];
  const int i = d >> 1;
  const float dv = expf((float)(2 * i) * KDIV);
  const float ang = tv * dv;
  const float te_time = (d & 1) ? cosf(ang) : sinf(ang);
  ushort_t* Xb = Xh + (size_t)b * T2 * DIN;
  const ushort_t tt = f2bf(te_time);
  Xb[(size_t)t * DIN + d] = f2bf(te_type);
  Xb[(size_t)t * DIN + DD + d] = tt;
  Xb[(size_t)(T_ + t) * DIN + d] = 0;
  Xb[(size_t)(T_ + t) * DIN + DD + d] = tt;
  Cur[((size_t)b * T_ + t) * DD + d] = 0.0f;
}

// ---------- weight transpose: W[hl][k][n] f32 -> WT[mat][n][k] bf16 ----------
__global__ __launch_bounds__(256) void k_transW(const float* __restrict__ Wq,
                                                const float* __restrict__ Wk,
                                                const float* __restrict__ Wv,
                                                ushort_t* __restrict__ WT) {
  const int mi = blockIdx.x;
  const int wsel = mi / 12, hl = mi % 12;
  const float* W = ((wsel == 0) ? Wq : (wsel == 1) ? Wk : Wv) + (size_t)hl * DIN * DD;
  const int t = blockIdx.y;
  const int k0 = (t >> 2) * 64, n0 = (t & 3) * 64;
  __shared__ float Ts[64][65];
  const int tid = threadIdx.x;
#pragma unroll
  for (int i = 0; i < 16; ++i) {
    const int idx = tid + i * 256;
    const int r = idx >> 6, c = idx & 63;
    Ts[r][c] = W[(size_t)(k0 + r) * DD + n0 + c];
  }
  __syncthreads();
  ushort_t* D = WT + (size_t)mi * DD * DIN;
#pragma unroll
  for (int i = 0; i < 16; ++i) {
    const int idx = tid + i * 256;
    const int rn = idx >> 6, ck = idx & 63;
    D[(size_t)(n0 + rn) * DIN + k0 + ck] = f2bf(Ts[ck][rn]);
  }
}

// ---------- TE precompute: TE^T[mat][col(256)][row(4096)] = time_emb @ W2 + bias ----------
// grid (32, 2, 36). time_emb read from Xh cols 256:512 (top rows; same for both halves).
__global__ __launch_bounds__(256) void k_te(const ushort_t* __restrict__ Xh,
                                            const ushort_t* __restrict__ WT,
                                            const float* __restrict__ bq,
                                            const float* __restrict__ bk,
                                            const float* __restrict__ bv,
                                            ushort_t* __restrict__ TE) {
  const int m0 = blockIdx.x * 128;     // row in [0,4096): b = row>>10, t = row&1023
  const int n0 = blockIdx.y * 128;
  const int mat = blockIdx.z;
  const int wsel = mat / 12, hl = mat % 12;
  const ushort_t* Bt = WT + (size_t)mat * DD * DIN + (size_t)n0 * DIN;
  const float* bias = ((wsel == 0) ? bq : (wsel == 1) ? bk : bv) + hl * DD;

  __shared__ ushort_t As[128 * 64];
  __shared__ ushort_t Bs[128 * 64];
  const int tid = threadIdx.x;
  const int w = tid >> 6, lane = tid & 63;
  const int wr = w >> 1, wc = w & 1;
  const int lr = lane & 15, kg = lane >> 4;

  f32x4 acc[4][4];
  const f32x4 z4 = {0.f, 0.f, 0.f, 0.f};
#pragma unroll
  for (int a = 0; a < 4; ++a)
#pragma unroll
    for (int c = 0; c < 4; ++c) acc[a][c] = z4;

  for (int k0 = 0; k0 < 256; k0 += 64) {
#pragma unroll
    for (int i = 0; i < 4; ++i) {
      const int idx = tid + i * 256;
      const int row = idx >> 3, ch = idx & 7;
      const int db = row * 128 + ((ch * 16) ^ ((row & 7) << 4));
      const int m = m0 + row;
      const size_t xrow = (size_t)(m >> 10) * T2 + (m & 1023);
      uint4 va = *(const uint4*)&Xh[xrow * DIN + DD + k0 + ch * 8];
      *(uint4*)((char*)As + db) = va;
      uint4 vb = *(const uint4*)&Bt[(size_t)row * DIN + DD + k0 + ch * 8];
      *(uint4*)((char*)Bs + db) = vb;
    }
    __syncthreads();
#pragma unroll
    for (int kk = 0; kk < 2; ++kk) {
      short8 af[4], bfr[4];
      const int cb = kk * 64 + kg * 16;
#pragma unroll
      for (int mi = 0; mi < 4; ++mi) {
        const int row = wr * 64 + mi * 16 + lr;
        af[mi] = *(const short8*)((const char*)As + row * 128 + (cb ^ ((row & 7) << 4)));
      }
#pragma unroll
      for (int ni = 0; ni < 4; ++ni) {
        const int row = wc * 64 + ni * 16 + lr;
        bfr[ni] = *(const short8*)((const char*)Bs + row * 128 + (cb ^ ((row & 7) << 4)));
      }
#pragma unroll
      for (int mi = 0; mi < 4; ++mi)
#pragma unroll
        for (int ni = 0; ni < 4; ++ni)
          acc[mi][ni] = __builtin_amdgcn_mfma_f32_16x16x32_bf16(af[mi], bfr[ni], acc[mi][ni], 0, 0, 0);
    }
    __syncthreads();
  }
#pragma unroll
  for (int mi = 0; mi < 4; ++mi)
#pragma unroll
    for (int ni = 0; ni < 4; ++ni) {
      const int col = n0 + wc * 64 + ni * 16 + lr;
      const float bcol = bias[col];
      const int rbase = m0 + wr * 64 + mi * 16 + kg * 4;
      us4v pk;
#pragma unroll
      for (int r = 0; r < 4; ++r) pk[r] = f2bf(acc[mi][ni][r] + bcol);
      *(us4v*)&TE[((size_t)mat * DD + col) * 4096 + rbase] = pk;
    }
}

// ---------- QKV GEMM (K=256 variable part) + TE add; V pi32-tiled ----------
// curZero: l==0 -> bottom-half blocks skip the GEMM (cur==0), output = TE.
__global__ __launch_bounds__(256) void k_qkv(const ushort_t* __restrict__ Xh,
                                             const ushort_t* __restrict__ WT,
                                             const ushort_t* __restrict__ TE,
                                             ushort_t* __restrict__ Qh,
                                             ushort_t* __restrict__ Kh,
                                             ushort_t* __restrict__ VTt,
                                             int hl, int curZero) {
  const int m0 = blockIdx.x * 128;
  const int n0 = blockIdx.y * 128;
  const int wsel = blockIdx.z;
  const int mat = wsel * 12 + hl;
  const ushort_t* Bt = WT + (size_t)mat * DD * DIN + (size_t)n0 * DIN;
  const int b2 = m0 >> 11;
  const int mloc = m0 & 2047;
  const bool isBottom = mloc >= 1024;
  const int teBase = b2 * 1024 + (m0 & 1023);

  __shared__ ushort_t As[128 * 64];
  __shared__ ushort_t Bs[128 * 64];
  const int tid = threadIdx.x;
  const int w = tid >> 6, lane = tid & 63;
  const int wr = w >> 1, wc = w & 1;
  const int lr = lane & 15, kg = lane >> 4;

  f32x4 acc[4][4];
  const f32x4 z4 = {0.f, 0.f, 0.f, 0.f};
#pragma unroll
  for (int a = 0; a < 4; ++a)
#pragma unroll
    for (int c = 0; c < 4; ++c) acc[a][c] = z4;

  if (!(curZero && isBottom)) {
    for (int k0 = 0; k0 < 256; k0 += 64) {
#pragma unroll
      for (int i = 0; i < 4; ++i) {
        const int idx = tid + i * 256;
        const int row = idx >> 3, ch = idx & 7;
        const int db = row * 128 + ((ch * 16) ^ ((row & 7) << 4));
        uint4 va = *(const uint4*)&Xh[(size_t)(m0 + row) * DIN + k0 + ch * 8];
        *(uint4*)((char*)As + db) = va;
        uint4 vb = *(const uint4*)&Bt[(size_t)row * DIN + k0 + ch * 8];
        *(uint4*)((char*)Bs + db) = vb;
      }
      __syncthreads();
#pragma unroll
      for (int kk = 0; kk < 2; ++kk) {
        short8 af[4], bfr[4];
        const int cb = kk * 64 + kg * 16;
#pragma unroll
        for (int mi = 0; mi < 4; ++mi) {
          const int row = wr * 64 + mi * 16 + lr;
          af[mi] = *(const short8*)((const char*)As + row * 128 + (cb ^ ((row & 7) << 4)));
        }
#pragma unroll
        for (int ni = 0; ni < 4; ++ni) {
          const int row = wc * 64 + ni * 16 + lr;
          bfr[ni] = *(const short8*)((const char*)Bs + row * 128 + (cb ^ ((row & 7) << 4)));
        }
#pragma unroll
        for (int mi = 0; mi < 4; ++mi)
#pragma unroll
          for (int ni = 0; ni < 4; ++ni)
            acc[mi][ni] = __builtin_amdgcn_mfma_f32_16x16x32_bf16(af[mi], bfr[ni], acc[mi][ni], 0, 0, 0);
      }
      __syncthreads();
    }
  }

  // epilogue: add TE^T (bias included), then store
#pragma unroll
  for (int mi = 0; mi < 4; ++mi)
#pragma unroll
    for (int ni = 0; ni < 4; ++ni) {
      const int col = n0 + wc * 64 + ni * 16 + lr;
      const int rloc = wr * 64 + mi * 16 + kg * 4;
      us4v te4 = *(const us4v*)&TE[((size_t)mat * DD + col) * 4096 + teBase + rloc];
      float v[4];
#pragma unroll
      for (int r = 0; r < 4; ++r) v[r] = acc[mi][ni][r] + bf2f(te4[r]);
      if (wsel < 2) {
        ushort_t* C = (wsel == 0) ? Qh : Kh;
        const int rbase = m0 + rloc;
#pragma unroll
        for (int r = 0; r < 4; ++r)
          C[(size_t)(rbase + r) * DD + col] = f2bf(v[r]);
      } else {
        const int t32 = (mloc >> 5) + wr * 2 + (mi >> 1);
        const int jloc = kg * 8 + (mi & 1) * 4;
        uint2 pk;
        pk.x = pack2(v[0], v[1]);
        pk.y = pack2(v[2], v[3]);
        *(uint2*)(VTt + ((size_t)(b2 * 64 + t32)) * (DD * 32) + col * 32 + jloc) = pk;
      }
    }
}

// ---------- flash partial: both halves share staged tiles ----------
// grid 640 = 5 seg-slots x (32 chunks x 4 batches); dead slots exit.
// Block: 4 waves = {top,bottom} x {rows 0-15,16-31} of chunk tc (64 q-rows).
// Single-seg chunks (tc<=6) do the epilogue (+row0 fold) directly.
__global__ __launch_bounds__(256, 2) void k_fpart(const ushort_t* __restrict__ Qh,
                                                  const ushort_t* __restrict__ Kh,
                                                  const ushort_t* __restrict__ VTt,
                                                  float* __restrict__ Cur,
                                                  ushort_t* __restrict__ Xh,
                                                  float* __restrict__ out,
                                                  const float* __restrict__ nw,
                                                  const float* __restrict__ nb,
                                                  ushort_t* __restrict__ PartO,
                                                  float* __restrict__ PartML,
                                                  int lastLayer, int h) {
  __shared__ char lds[66560];   // K dbuf 2x16KB | V dbuf 2x16KB @32768 | red @65536
  const int tid = threadIdx.x;
  const int bx = blockIdx.x;
  const int seg = bx >> 7;
  const int rem = bx & 127;
  const int b = rem & 3;
  const int tc = 31 - (rem >> 2);       // heavy chunks first
  const int nt = tc + 2;                // causal 0..tc + diag
  const int nseg = (nt + SEGL - 1) / SEGL;
  if (seg >= nseg) return;
  const int kt0 = seg * SEGL;
  const int klen = (nt - kt0 < SEGL) ? (nt - kt0) : SEGL;
  const int dt = 32 + tc;

  const int w = tid >> 6, lane = tid & 63;
  const int kg = lane >> 4, lr = lane & 15;
  const int half = w >> 1;
  const int tq = (w & 1) * 16 + lr;     // 0..31 within chunk
  const int t = tc * 32 + tq;
  const int r0 = (half ? T_ : 0) + t;
  const size_t bT2 = (size_t)b * T2;

  short8 qf[8];
  {
    const ushort_t* qb = Qh + (bT2 + r0) * DD + kg * 8;
#pragma unroll
    for (int kk = 0; kk < 8; ++kk) qf[kk] = *(const short8*)(qb + kk * 32);
  }

  const f32x4 z4 = {0.f, 0.f, 0.f, 0.f};
  f32x4 acc_o[16];
#pragma unroll
  for (int db = 0; db < 16; ++db) acc_o[db] = z4;
  float m_run = -1e30f, l_run = 0.f;

#define STAGE(BUF, TILE)                                                                  \
  {                                                                                       \
    const int _t = (TILE);                                                                \
    const char* Vt = (const char*)VTt + ((size_t)(b * 64 + _t)) * 16384;                  \
    _Pragma("unroll") for (int s = 0; s < 4; ++s) {                                       \
      const int c = w * 4 + s;                                                            \
      const int row2 = (c << 1) | (lane >> 5);                                            \
      const int cc2 = lane & 31;                                                          \
      async_copy16((const char*)Kh + ((bT2 + _t * 32 + row2) * DD) * 2 +                  \
                       ((cc2 * 16) ^ ((row2 & 7) << 4)),                                  \
                   lds + (BUF) * 16384 + c * 1024);                                       \
      async_copy16(Vt + c * 1024 + lane * 16,                                             \
                   lds + 32768 + (BUF) * 16384 + c * 1024);                               \
    }                                                                                     \
  }
#define TILEOF(KT) (((KT) <= tc) ? (KT) : dt)

  STAGE(0, TILEOF(kt0));

  union U8 { uint4 u; short8 s; };

  for (int ktl = 0; ktl < klen; ++ktl) {
    const int kt = kt0 + ktl;
    const int tile = TILEOF(kt);
    const bool isDiag = (kt > tc);

    if (ktl + 1 < klen) {
      STAGE((ktl + 1) & 1, TILEOF(kt + 1));
      asm volatile("s_waitcnt vmcnt(8)" ::: "memory");
    } else {
      asm volatile("s_waitcnt vmcnt(0)" ::: "memory");
    }
    __builtin_amdgcn_s_barrier();
    asm volatile("" ::: "memory");

    if (!(isDiag && half == 0)) {
      const char* KsC = lds + (ktl & 1) * 16384;
      const char* VsC = lds + 32768 + (ktl & 1) * 16384;

      // QK^T (swapped): S^T[j = tile*32 + jb*16 + kg*4 + r][q = lr]
      f32x4 sa[2];
#pragma unroll
      for (int jb = 0; jb < 2; ++jb) {
        sa[jb] = z4;
        const int rowj = jb * 16 + lr;
        const int base = rowj * 512;
        const int swj = (rowj & 7) << 4;
#pragma unroll
        for (int kk = 0; kk < 8; ++kk) {
          short8 kf = *(const short8*)(KsC + base + ((kk * 64 + kg * 16) ^ swj));
          sa[jb] = __builtin_amdgcn_mfma_f32_16x16x32_bf16(kf, qf[kk], sa[jb], 0, 0, 0);
        }
      }

      // mask + scale + online softmax with defer-max
      float sv[8];
      float tmax = -1e30f;
#pragma unroll
      for (int jb = 0; jb < 2; ++jb)
#pragma unroll
        for (int rr = 0; rr < 4; ++rr) {
          const int jl = jb * 16 + kg * 4 + rr;
          const bool valid = isDiag ? (jl == tq) : ((tile * 32 + jl) < t);
          const float x = valid ? sa[jb][rr] * 0.0625f : -1e30f;
          sv[jb * 4 + rr] = x;
          tmax = fmaxf(tmax, x);
        }
      tmax = fmaxf(tmax, __shfl_xor(tmax, 16, 64));
      tmax = fmaxf(tmax, __shfl_xor(tmax, 32, 64));
      if (tmax > m_run + 8.0f) {
        const float fac = __expf(m_run - tmax);
        m_run = tmax;
        l_run *= fac;
#pragma unroll
        for (int db = 0; db < 16; ++db) acc_o[db] *= fac;
      }
      float p[8];
      float psum = 0.f;
#pragma unroll
      for (int e = 0; e < 8; ++e) {
        const float pe = (sv[e] > -1e29f) ? __expf(sv[e] - m_run) : 0.0f;
        p[e] = pe;
        psum += pe;
      }
      psum += __shfl_xor(psum, 16, 64);
      psum += __shfl_xor(psum, 32, 64);
      l_run += psum;

      U8 pf;
      pf.u.x = cvtpk(p[0], p[1]);
      pf.u.y = cvtpk(p[2], p[3]);
      pf.u.z = cvtpk(p[4], p[5]);
      pf.u.w = cvtpk(p[6], p[7]);

      // PV: O^T += V^T * P^T (K=32), V from LDS pi32 layout
#pragma unroll
      for (int db = 0; db < 16; ++db) {
        U8 vf;
        vf.u = *(const uint4*)(VsC + (db * 16 + lr) * 64 + kg * 16);
        acc_o[db] = __builtin_amdgcn_mfma_f32_16x16x32_bf16(vf.s, pf.s, acc_o[db], 0, 0, 0);
      }
    }

    __builtin_amdgcn_s_barrier();
    asm volatile("" ::: "memory");
  }
#undef STAGE
#undef TILEOF

  if (nseg > 1) {
    // ---------- write partial (bf16 O, f32 m/l; 64-row slot) ----------
    const int slot = (b * 32 + tc) * 5 + seg;
    const int row = half * 32 + tq;
    float* pml = PartML + slot * 128;
    if (kg == 0) { pml[row] = m_run; pml[64 + row] = l_run; }
    ushort_t* po = PartO + ((size_t)slot) * (64 * 256) + row * 256 + kg * 4;
#pragma unroll
    for (int db = 0; db < 16; ++db) {
      us4v o;
#pragma unroll
      for (int rr = 0; rr < 4; ++rr) o[rr] = f2bf(acc_o[db][rr]);
      *(us4v*)(po + db * 16) = o;
    }
    return;
  }

  // ---------- single-segment: direct epilogue ----------
  const float oinv = 1.0f / l_run;   // t==0 (top): l==0 -> store skipped

  if (!half) {
    if (t != 0) {
      ushort_t* xp = Xh + (bT2 + t) * DIN + kg * 4;
#pragma unroll
      for (int db = 0; db < 16; ++db) {
        us4v o;
#pragma unroll
        for (int rr = 0; rr < 4; ++rr) o[rr] = f2bf(acc_o[db][rr] * oinv);
        *(us4v*)(xp + db * 16) = o;
      }
    }
  } else {
    float* cp = Cur + ((size_t)b * T_ + t) * DD + kg * 4;
    float s1 = 0.f, s2 = 0.f;
#pragma unroll
    for (int db = 0; db < 16; ++db) {
      f32x4 c4 = *(const f32x4*)(cp + db * 16);
#pragma unroll
      for (int rr = 0; rr < 4; ++rr) {
        const float x = tanhf(acc_o[db][rr] * oinv) + c4[rr];
        acc_o[db][rr] = x;
        s1 += x;
        s2 += x * x;
      }
    }
    s1 += __shfl_xor(s1, 16, 64); s1 += __shfl_xor(s1, 32, 64);
    s2 += __shfl_xor(s2, 16, 64); s2 += __shfl_xor(s2, 32, 64);
    const float mean = s1 * (1.0f / 256.0f);
    const float var = s2 * (1.0f / 256.0f) - mean * mean;
    const float rinv = rsqrtf(var + LNEPS);
    ushort_t* xp = Xh + (bT2 + T_ + t) * DIN + kg * 4;
    if (lastLayer) {
      float* op = out + ((size_t)b * T_ + t) * (DD * 4) + h * DD + kg * 4;
      const us4v zz = {0, 0, 0, 0};
      const f32x4 zf = {0.f, 0.f, 0.f, 0.f};
#pragma unroll
      for (int db = 0; db < 16; ++db) {
        f32x4 w4 = *(const f32x4*)&nw[db * 16 + kg * 4];
        f32x4 b4 = *(const f32x4*)&nb[db * 16 + kg * 4];
        f32x4 y;
#pragma unroll
        for (int rr = 0; rr < 4; ++rr) y[rr] = (acc_o[db][rr] - mean) * rinv * w4[rr] + b4[rr];
        *(f32x4*)(op + db * 16) = y;
        *(f32x4*)(cp + db * 16) = zf;
        *(us4v*)(xp + db * 16) = zz;
      }
    } else {
#pragma unroll
      for (int db = 0; db < 16; ++db) {
        f32x4 w4 = *(const f32x4*)&nw[db * 16 + kg * 4];
        f32x4 b4 = *(const f32x4*)&nb[db * 16 + kg * 4];
        f32x4 y;
        us4v yh;
#pragma unroll
        for (int rr = 0; rr < 4; ++rr) {
          y[rr] = (acc_o[db][rr] - mean) * rinv * w4[rr] + b4[rr];
          yh[rr] = f2bf(y[rr]);
        }
        *(f32x4*)(cp + db * 16) = y;
        *(us4v*)(xp + db * 16) = yh;
      }
    }
  }

  // ---------- row0 mean-V fold (tc<4; all single-seg) ----------
  if (tc < 4) {
    __syncthreads();
    float* red = (float*)(lds + 65536);
    const int col = tc * 64 + (tid & 63);
    const int q4 = tid >> 6;
    float s = 0.f;
    for (int tl = q4 * 16; tl < q4 * 16 + 16; ++tl) {
      const ushort_t* vp = VTt + ((size_t)(b * 64 + tl)) * 8192 + col * 32;
#pragma unroll
      for (int j = 0; j < 32; j += 8) {
        uint4 v = *(const uint4*)(vp + j);
        const uint_t vs[4] = {v.x, v.y, v.z, v.w};
#pragma unroll
        for (int q = 0; q < 4; ++q) {
          s += __uint_as_float(vs[q] << 16);
          s += __uint_as_float(vs[q] & 0xffff0000u);
        }
      }
    }
    red[q4 * 64 + (tid & 63)] = s;
    __syncthreads();
    if (tid < 64)
      Xh[bT2 * DIN + tc * 64 + tid] =
          f2bf((red[tid] + red[64 + tid] + red[128 + tid] + red[192 + tid]) * (1.0f / 2048.0f));
  }
}

// ---------- merge + epilogue for multi-seg chunks (tc>=7): grid 100 x 256 ----------
__global__ __launch_bounds__(256) void k_merge(float* __restrict__ Cur,
                                               ushort_t* __restrict__ Xh,
                                               float* __restrict__ out,
                                               const float* __restrict__ nw,
                                               const float* __restrict__ nb,
                                               const ushort_t* __restrict__ PartO,
                                               const float* __restrict__ PartML,
                                               int lastLayer, int h) {
  const int tid = threadIdx.x;
  const int bx = blockIdx.x;
  const int b = bx & 3;
  const int tc = 7 + (bx >> 2);
  const int nt = tc + 2;
  const int nseg = (nt + SEGL - 1) / SEGL;
  const int slot0 = (b * 32 + tc) * 5;

  const int w = tid >> 6, lane = tid & 63;
  const int kg = lane >> 4, lr = lane & 15;
  const int half = w >> 1;
  const int tq = (w & 1) * 16 + lr;
  const int t = tc * 32 + tq;
  const int row = half * 32 + tq;
  const size_t bT2 = (size_t)b * T2;
  const f32x4 z4 = {0.f, 0.f, 0.f, 0.f};

  float mstar = -1e30f;
  for (int s = 0; s < nseg; ++s)
    mstar = fmaxf(mstar, PartML[(slot0 + s) * 128 + row]);
  float l_run = 0.f;
  f32x4 acc_o[16];
#pragma unroll
  for (int db = 0; db < 16; ++db) acc_o[db] = z4;
  for (int s = 0; s < nseg; ++s) {
    const float* pml = PartML + (slot0 + s) * 128;
    const float f = __expf(pml[row] - mstar);
    l_run += f * pml[64 + row];
    const ushort_t* po = PartO + ((size_t)(slot0 + s)) * (64 * 256) + row * 256 + kg * 4;
#pragma unroll
    for (int db = 0; db < 16; ++db) {
      us4v v4 = *(const us4v*)(po + db * 16);
#pragma unroll
      for (int q = 0; q < 4; ++q) acc_o[db][q] += f * bf2f(v4[q]);
    }
  }

  const float oinv = 1.0f / l_run;

  if (!half) {
    ushort_t* xp = Xh + (bT2 + t) * DIN + kg * 4;
#pragma unroll
    for (int db = 0; db < 16; ++db) {
      us4v o;
#pragma unroll
      for (int rr = 0; rr < 4; ++rr) o[rr] = f2bf(acc_o[db][rr] * oinv);
      *(us4v*)(xp + db * 16) = o;
    }
  } else {
    float* cp = Cur + ((size_t)b * T_ + t) * DD + kg * 4;
    float s1 = 0.f, s2 = 0.f;
#pragma unroll
    for (int db = 0; db < 16; ++db) {
      f32x4 c4 = *(const f32x4*)(cp + db * 16);
#pragma unroll
      for (int rr = 0; rr < 4; ++rr) {
        const float x = tanhf(acc_o[db][rr] * oinv) + c4[rr];
        acc_o[db][rr] = x;
        s1 += x;
        s2 += x * x;
      }
    }
    s1 += __shfl_xor(s1, 16, 64); s1 += __shfl_xor(s1, 32, 64);
    s2 += __shfl_xor(s2, 16, 64); s2 += __shfl_xor(s2, 32, 64);
    const float mean = s1 * (1.0f / 256.0f);
    const float var = s2 * (1.0f / 256.0f) - mean * mean;
    const float rinv = rsqrtf(var + LNEPS);
    ushort_t* xp = Xh + (bT2 + T_ + t) * DIN + kg * 4;
    if (lastLayer) {
      float* op = out + ((size_t)b * T_ + t) * (DD * 4) + h * DD + kg * 4;
      const us4v zz = {0, 0, 0, 0};
      const f32x4 zf = {0.f, 0.f, 0.f, 0.f};
#pragma unroll
      for (int db = 0; db < 16; ++db) {
        f32x4 w4 = *(const f32x4*)&nw[db * 16 + kg * 4];
        f32x4 b4 = *(const f32x4*)&nb[db * 16 + kg * 4];
        f32x4 y;
#pragma unroll
        for (int rr = 0; rr < 4; ++rr) y[rr] = (acc_o[db][rr] - mean) * rinv * w4[rr] + b4[rr];
        *(f32x4*)(op + db * 16) = y;
        *(f32x4*)(cp + db * 16) = zf;
        *(us4v*)(xp + db * 16) = zz;
      }
    } else {
#pragma unroll
      for (int db = 0; db < 16; ++db) {
        f32x4 w4 = *(const f32x4*)&nw[db * 16 + kg * 4];
        f32x4 b4 = *(const f32x4*)&nb[db * 16 + kg * 4];
        f32x4 y;
        us4v yh;
#pragma unroll
        for (int rr = 0; rr < 4; ++rr) {
          y[rr] = (acc_o[db][rr] - mean) * rinv * w4[rr] + b4[rr];
          yh[rr] = f2bf(y[rr]);
        }
        *(f32x4*)(cp + db * 16) = y;
        *(us4v*)(xp + db * 16) = yh;
      }
    }
  }
}

extern "C" void kernel_launch(void* const* d_in, const int* in_sizes, int n_in,
                              void* d_out, int out_size, void* d_ws, size_t ws_size,
                              hipStream_t stream) {
  const float* ev = (const float*)d_in[0];
  const float* tm = (const float*)d_in[1];
  const float* Wt = (const float*)d_in[3];
  const float* bt = (const float*)d_in[4];
  const float* Wq = (const float*)d_in[5];
  const float* bq = (const float*)d_in[6];
  const float* Wk = (const float*)d_in[7];
  const float* bk = (const float*)d_in[8];
  const float* Wv = (const float*)d_in[9];
  const float* bv = (const float*)d_in[10];
  const float* nw = (const float*)d_in[11];
  const float* nb = (const float*)d_in[12];
  float* out = (float*)d_out;

  char* p = (char*)d_ws;
  ushort_t* Xh  = (ushort_t*)p; p += (size_t)BB * T2 * DIN * 2;   // 8.39 MB
  ushort_t* Qh  = (ushort_t*)p; p += (size_t)BB * T2 * DD * 2;    // 4.19 MB
  ushort_t* Kh  = (ushort_t*)p; p += (size_t)BB * T2 * DD * 2;
  ushort_t* VTt = (ushort_t*)p; p += (size_t)BB * T2 * DD * 2;    // pi32-tiled V
  float* Cur    = (float*)p;    p += (size_t)BB * T_ * DD * 4;    // 4.19 MB
  ushort_t* WT  = (ushort_t*)p; p += (size_t)36 * DD * DIN * 2;   // 9.44 MB
  ushort_t* TE  = (ushort_t*)p; p += (size_t)36 * DD * 4096 * 2;  // 75.5 MB (TE^T)
  ushort_t* PartO = (ushort_t*)p; p += (size_t)640 * 64 * 256 * 2; // 21.0 MB
  float* PartML = (float*)p;                                       // 0.33 MB

  k_init<<<BB * T_, 256, 0, stream>>>(ev, tm, Wt, bt, Xh, Cur);
  k_transW<<<dim3(36, 32), 256, 0, stream>>>(Wq, Wk, Wv, WT);
  k_te<<<dim3(32, 2, 36), 256, 0, stream>>>(Xh, WT, bq, bk, bv, TE);

  for (int h = 0; h < 4; ++h) {
    for (int l = 0; l < 3; ++l) {
      const int hl = h * 3 + l;
      k_qkv<<<dim3(64, 2, 3), 256, 0, stream>>>(Xh, WT, TE, Qh, Kh, VTt, hl,
                                                (l == 0) ? 1 : 0);
      k_fpart<<<640, 256, 0, stream>>>(Qh, Kh, VTt, Cur, Xh, out, nw, nb,
                                       PartO, PartML, (l == 2) ? 1 : 0, h);
      k_merge<<<100, 256, 0, stream>>>(Cur, Xh, out, nw, nb,
                                       PartO, PartML, (l == 2) ? 1 : 0, h);
    }
  }
}

// Round 18
// 702.787 us; speedup vs baseline: 1.1007x; 1.1007x over previous
//
#include <hip/hip_runtime.h>

typedef __attribute__((ext_vector_type(8))) short short8;
typedef __attribute__((ext_vector_type(4))) float f32x4;
typedef __attribute__((ext_vector_type(4))) unsigned short us4v;
typedef unsigned short ushort_t;
typedef unsigned int uint_t;

#define BB 4
#define T_ 1024
#define T2 2048
#define DD 256
#define DIN 512
#define NMARK 64
#define LNEPS 1e-5f
#define KDIV (-0.035977892078032f)
#define SEGL 8

__device__ __forceinline__ ushort_t f2bf(float f) {
  unsigned int u = __float_as_uint(f);
  unsigned int r = (u + 0x7fffu + ((u >> 16) & 1u)) >> 16;
  return (ushort_t)r;
}
__device__ __forceinline__ float bf2f(ushort_t v) {
  return __uint_as_float(((uint_t)v) << 16);
}
__device__ __forceinline__ uint_t pack2(float a, float b) {
  return (uint_t)f2bf(a) | ((uint_t)f2bf(b) << 16);
}
__device__ __forceinline__ uint_t cvtpk(float lo, float hi) {
  uint_t r;
  asm("v_cvt_pk_bf16_f32 %0, %1, %2" : "=v"(r) : "v"(lo), "v"(hi));
  return r;
}

typedef const __attribute__((address_space(1))) unsigned int* as1cu32;
typedef __attribute__((address_space(3))) unsigned int* as3u32;
__device__ __forceinline__ void async_copy16(const void* g, void* l) {
  __builtin_amdgcn_global_load_lds((as1cu32)g, (as3u32)l, 16, 0, 0);
}

// ---------- init: type/time embeddings -> Xh (bf16), Cur = 0 ----------
__global__ __launch_bounds__(256) void k_init(const float* __restrict__ ev,
                                              const float* __restrict__ tm,
                                              const float* __restrict__ Wt,
                                              const float* __restrict__ bt,
                                              ushort_t* __restrict__ Xh,
                                              float* __restrict__ Cur) {
  const int btq = blockIdx.x;
  const int b = btq >> 10;
  const int t = btq & 1023;
  const int d = threadIdx.x;
  __shared__ float evs[NMARK];
  if (d < NMARK) evs[d] = ev[(size_t)btq * NMARK + d];
  __syncthreads();
  float s = bt[d];
#pragma unroll
  for (int m = 0; m < NMARK; ++m) s += evs[m] * Wt[m * DD + d];
  const float te_type = tanhf(s);
  const float tv = tm[btq];
  const int i = d >> 1;
  const float dv = expf((float)(2 * i) * KDIV);
  const float ang = tv * dv;
  const float te_time = (d & 1) ? cosf(ang) : sinf(ang);
  ushort_t* Xb = Xh + (size_t)b * T2 * DIN;
  const ushort_t tt = f2bf(te_time);
  Xb[(size_t)t * DIN + d] = f2bf(te_type);
  Xb[(size_t)t * DIN + DD + d] = tt;
  Xb[(size_t)(T_ + t) * DIN + d] = 0;
  Xb[(size_t)(T_ + t) * DIN + DD + d] = tt;
  Cur[((size_t)b * T_ + t) * DD + d] = 0.0f;
}

// ---------- weight transpose: W[hl][k][n] f32 -> WT[mat][n][k] bf16 ----------
__global__ __launch_bounds__(256) void k_transW(const float* __restrict__ Wq,
                                                const float* __restrict__ Wk,
                                                const float* __restrict__ Wv,
                                                ushort_t* __restrict__ WT) {
  const int mi = blockIdx.x;
  const int wsel = mi / 12, hl = mi % 12;
  const float* W = ((wsel == 0) ? Wq : (wsel == 1) ? Wk : Wv) + (size_t)hl * DIN * DD;
  const int t = blockIdx.y;
  const int k0 = (t >> 2) * 64, n0 = (t & 3) * 64;
  __shared__ float Ts[64][65];
  const int tid = threadIdx.x;
#pragma unroll
  for (int i = 0; i < 16; ++i) {
    const int idx = tid + i * 256;
    const int r = idx >> 6, c = idx & 63;
    Ts[r][c] = W[(size_t)(k0 + r) * DD + n0 + c];
  }
  __syncthreads();
  ushort_t* D = WT + (size_t)mi * DD * DIN;
#pragma unroll
  for (int i = 0; i < 16; ++i) {
    const int idx = tid + i * 256;
    const int rn = idx >> 6, ck = idx & 63;
    D[(size_t)(n0 + rn) * DIN + k0 + ck] = f2bf(Ts[ck][rn]);
  }
}

// ---------- QKV GEMM: 64-row m-tiles, grid (128,2,3) = 768 blocks = 3/CU ----------
// V written pi32-permuted into 32-wide tiles. curZero: l==0 bottom rows have
// X cols 0:255 == 0 -> skip that K half.
__global__ __launch_bounds__(256) void k_qkv(const ushort_t* __restrict__ Xh,
                                             const ushort_t* __restrict__ WT,
                                             const float* __restrict__ bq,
                                             const float* __restrict__ bk,
                                             const float* __restrict__ bv,
                                             ushort_t* __restrict__ Qh,
                                             ushort_t* __restrict__ Kh,
                                             ushort_t* __restrict__ VTt,
                                             int hl, int curZero) {
  const int m0 = blockIdx.x * 64;
  const int n0 = blockIdx.y * 128;
  const int wsel = blockIdx.z;
  const ushort_t* Bt = WT + ((size_t)(wsel * 12 + hl)) * DD * DIN + (size_t)n0 * DIN;
  const float* bias = ((wsel == 0) ? bq : (wsel == 1) ? bk : bv) + hl * DD;
  const int b2 = m0 >> 11;
  const int mloc = m0 & 2047;
  const bool skipHalf = curZero && (mloc >= 1024);

  __shared__ ushort_t As[64 * 64];     // 8 KB
  __shared__ ushort_t Bs[128 * 64];    // 16 KB
  const int tid = threadIdx.x;
  const int w = tid >> 6, lane = tid & 63;
  const int lr = lane & 15, kg = lane >> 4;

  f32x4 acc[4][2];
  const f32x4 z4 = {0.f, 0.f, 0.f, 0.f};
#pragma unroll
  for (int a = 0; a < 4; ++a)
#pragma unroll
    for (int c = 0; c < 2; ++c) acc[a][c] = z4;

  for (int k0 = skipHalf ? 256 : 0; k0 < DIN; k0 += 64) {
#pragma unroll
    for (int i = 0; i < 2; ++i) {
      const int idx = tid + i * 256;
      const int row = idx >> 3, ch = idx & 7;
      const int db = row * 128 + ((ch * 16) ^ ((row & 7) << 4));
      uint4 va = *(const uint4*)&Xh[(size_t)(m0 + row) * DIN + k0 + ch * 8];
      *(uint4*)((char*)As + db) = va;
    }
#pragma unroll
    for (int i = 0; i < 4; ++i) {
      const int idx = tid + i * 256;
      const int row = idx >> 3, ch = idx & 7;
      const int db = row * 128 + ((ch * 16) ^ ((row & 7) << 4));
      uint4 vb = *(const uint4*)&Bt[(size_t)row * DIN + k0 + ch * 8];
      *(uint4*)((char*)Bs + db) = vb;
    }
    __syncthreads();
#pragma unroll
    for (int kk = 0; kk < 2; ++kk) {
      short8 af[4], bfr[2];
      const int cb = kk * 64 + kg * 16;
#pragma unroll
      for (int mi = 0; mi < 4; ++mi) {
        const int row = mi * 16 + lr;
        af[mi] = *(const short8*)((const char*)As + row * 128 + (cb ^ ((row & 7) << 4)));
      }
#pragma unroll
      for (int ni = 0; ni < 2; ++ni) {
        const int row = w * 32 + ni * 16 + lr;
        bfr[ni] = *(const short8*)((const char*)Bs + row * 128 + (cb ^ ((row & 7) << 4)));
      }
#pragma unroll
      for (int mi = 0; mi < 4; ++mi)
#pragma unroll
        for (int ni = 0; ni < 2; ++ni)
          acc[mi][ni] = __builtin_amdgcn_mfma_f32_16x16x32_bf16(af[mi], bfr[ni], acc[mi][ni], 0, 0, 0);
    }
    __syncthreads();
  }

  if (wsel < 2) {
    ushort_t* C = (wsel == 0) ? Qh : Kh;
#pragma unroll
    for (int mi = 0; mi < 4; ++mi)
#pragma unroll
      for (int ni = 0; ni < 2; ++ni) {
        const int col = n0 + w * 32 + ni * 16 + lr;
        const float bcol = bias[col];
        const int rbase = m0 + mi * 16 + kg * 4;
#pragma unroll
        for (int r = 0; r < 4; ++r)
          C[(size_t)(rbase + r) * DD + col] = f2bf(acc[mi][ni][r] + bcol);
      }
  } else {
#pragma unroll
    for (int mi = 0; mi < 4; ++mi)
#pragma unroll
      for (int ni = 0; ni < 2; ++ni) {
        const int col = n0 + w * 32 + ni * 16 + lr;
        const float bcol = bias[col];
        const int t32 = (mloc >> 5) + (mi >> 1);
        const int jloc = kg * 8 + (mi & 1) * 4;
        uint2 pk;
        pk.x = pack2(acc[mi][ni][0] + bcol, acc[mi][ni][1] + bcol);
        pk.y = pack2(acc[mi][ni][2] + bcol, acc[mi][ni][3] + bcol);
        *(uint2*)(VTt + ((size_t)(b2 * 64 + t32)) * (DD * 32) + col * 32 + jloc) = pk;
      }
  }
}

// ---------- flash partial: both halves share staged tiles ----------
// grid 640 = 5 seg-slots x (32 chunks x 4 batches); dead slots exit.
// Block: 4 waves = {top,bottom} x {rows 0-15,16-31} of chunk tc (64 q-rows).
// Single-seg chunks (tc<=6) do the epilogue (+row0 fold) directly.
__global__ __launch_bounds__(256, 2) void k_fpart(const ushort_t* __restrict__ Qh,
                                                  const ushort_t* __restrict__ Kh,
                                                  const ushort_t* __restrict__ VTt,
                                                  float* __restrict__ Cur,
                                                  ushort_t* __restrict__ Xh,
                                                  float* __restrict__ out,
                                                  const float* __restrict__ nw,
                                                  const float* __restrict__ nb,
                                                  ushort_t* __restrict__ PartO,
                                                  float* __restrict__ PartML,
                                                  int lastLayer, int h) {
  __shared__ char lds[66560];   // K dbuf 2x16KB | V dbuf 2x16KB @32768 | red @65536
  const int tid = threadIdx.x;
  const int bx = blockIdx.x;
  const int seg = bx >> 7;
  const int rem = bx & 127;
  const int b = rem & 3;
  const int tc = 31 - (rem >> 2);       // heavy chunks first
  const int nt = tc + 2;                // causal 0..tc + diag
  const int nseg = (nt + SEGL - 1) / SEGL;
  if (seg >= nseg) return;
  const int kt0 = seg * SEGL;
  const int klen = (nt - kt0 < SEGL) ? (nt - kt0) : SEGL;
  const int dt = 32 + tc;

  const int w = tid >> 6, lane = tid & 63;
  const int kg = lane >> 4, lr = lane & 15;
  const int half = w >> 1;
  const int tq = (w & 1) * 16 + lr;     // 0..31 within chunk
  const int t = tc * 32 + tq;
  const int r0 = (half ? T_ : 0) + t;
  const size_t bT2 = (size_t)b * T2;

  short8 qf[8];
  {
    const ushort_t* qb = Qh + (bT2 + r0) * DD + kg * 8;
#pragma unroll
    for (int kk = 0; kk < 8; ++kk) qf[kk] = *(const short8*)(qb + kk * 32);
  }

  const f32x4 z4 = {0.f, 0.f, 0.f, 0.f};
  f32x4 acc_o[16];
#pragma unroll
  for (int db = 0; db < 16; ++db) acc_o[db] = z4;
  float m_run = -1e30f, l_run = 0.f;

#define STAGE(BUF, TILE)                                                                  \
  {                                                                                       \
    const int _t = (TILE);                                                                \
    const char* Vt = (const char*)VTt + ((size_t)(b * 64 + _t)) * 16384;                  \
    _Pragma("unroll") for (int s = 0; s < 4; ++s) {                                       \
      const int c = w * 4 + s;                                                            \
      const int row2 = (c << 1) | (lane >> 5);                                            \
      const int cc2 = lane & 31;                                                          \
      async_copy16((const char*)Kh + ((bT2 + _t * 32 + row2) * DD) * 2 +                  \
                       ((cc2 * 16) ^ ((row2 & 7) << 4)),                                  \
                   lds + (BUF) * 16384 + c * 1024);                                       \
      async_copy16(Vt + c * 1024 + lane * 16,                                             \
                   lds + 32768 + (BUF) * 16384 + c * 1024);                               \
    }                                                                                     \
  }
#define TILEOF(KT) (((KT) <= tc) ? (KT) : dt)

  STAGE(0, TILEOF(kt0));

  union U8 { uint4 u; short8 s; };

  for (int ktl = 0; ktl < klen; ++ktl) {
    const int kt = kt0 + ktl;
    const int tile = TILEOF(kt);
    const bool isDiag = (kt > tc);

    if (ktl + 1 < klen) {
      STAGE((ktl + 1) & 1, TILEOF(kt + 1));
      asm volatile("s_waitcnt vmcnt(8)" ::: "memory");
    } else {
      asm volatile("s_waitcnt vmcnt(0)" ::: "memory");
    }
    __builtin_amdgcn_s_barrier();
    asm volatile("" ::: "memory");

    if (!(isDiag && half == 0)) {
      const char* KsC = lds + (ktl & 1) * 16384;
      const char* VsC = lds + 32768 + (ktl & 1) * 16384;

      // QK^T (swapped): S^T[j = tile*32 + jb*16 + kg*4 + r][q = lr]
      f32x4 sa[2];
#pragma unroll
      for (int jb = 0; jb < 2; ++jb) {
        sa[jb] = z4;
        const int rowj = jb * 16 + lr;
        const int base = rowj * 512;
        const int swj = (rowj & 7) << 4;
#pragma unroll
        for (int kk = 0; kk < 8; ++kk) {
          short8 kf = *(const short8*)(KsC + base + ((kk * 64 + kg * 16) ^ swj));
          sa[jb] = __builtin_amdgcn_mfma_f32_16x16x32_bf16(kf, qf[kk], sa[jb], 0, 0, 0);
        }
      }

      // mask + scale + online softmax with defer-max
      float sv[8];
      float tmax = -1e30f;
#pragma unroll
      for (int jb = 0; jb < 2; ++jb)
#pragma unroll
        for (int rr = 0; rr < 4; ++rr) {
          const int jl = jb * 16 + kg * 4 + rr;
          const bool valid = isDiag ? (jl == tq) : ((tile * 32 + jl) < t);
          const float x = valid ? sa[jb][rr] * 0.0625f : -1e30f;
          sv[jb * 4 + rr] = x;
          tmax = fmaxf(tmax, x);
        }
      tmax = fmaxf(tmax, __shfl_xor(tmax, 16, 64));
      tmax = fmaxf(tmax, __shfl_xor(tmax, 32, 64));
      if (tmax > m_run + 8.0f) {
        const float fac = __expf(m_run - tmax);
        m_run = tmax;
        l_run *= fac;
#pragma unroll
        for (int db = 0; db < 16; ++db) acc_o[db] *= fac;
      }
      float p[8];
      float psum = 0.f;
#pragma unroll
      for (int e = 0; e < 8; ++e) {
        const float pe = (sv[e] > -1e29f) ? __expf(sv[e] - m_run) : 0.0f;
        p[e] = pe;
        psum += pe;
      }
      psum += __shfl_xor(psum, 16, 64);
      psum += __shfl_xor(psum, 32, 64);
      l_run += psum;

      U8 pf;
      pf.u.x = cvtpk(p[0], p[1]);
      pf.u.y = cvtpk(p[2], p[3]);
      pf.u.z = cvtpk(p[4], p[5]);
      pf.u.w = cvtpk(p[6], p[7]);

      // PV: O^T += V^T * P^T (K=32), V from LDS pi32 layout
#pragma unroll
      for (int db = 0; db < 16; ++db) {
        U8 vf;
        vf.u = *(const uint4*)(VsC + (db * 16 + lr) * 64 + kg * 16);
        acc_o[db] = __builtin_amdgcn_mfma_f32_16x16x32_bf16(vf.s, pf.s, acc_o[db], 0, 0, 0);
      }
    }

    __builtin_amdgcn_s_barrier();
    asm volatile("" ::: "memory");
  }
#undef STAGE
#undef TILEOF

  if (nseg > 1) {
    // ---------- write partial (bf16 O, f32 m/l; 64-row slot) ----------
    const int slot = (b * 32 + tc) * 5 + seg;
    const int row = half * 32 + tq;
    float* pml = PartML + slot * 128;
    if (kg == 0) { pml[row] = m_run; pml[64 + row] = l_run; }
    ushort_t* po = PartO + ((size_t)slot) * (64 * 256) + row * 256 + kg * 4;
#pragma unroll
    for (int db = 0; db < 16; ++db) {
      us4v o;
#pragma unroll
      for (int rr = 0; rr < 4; ++rr) o[rr] = f2bf(acc_o[db][rr]);
      *(us4v*)(po + db * 16) = o;
    }
    return;
  }

  // ---------- single-segment: direct epilogue ----------
  const float oinv = 1.0f / l_run;   // t==0 (top): l==0 -> store skipped

  if (!half) {
    if (t != 0) {
      ushort_t* xp = Xh + (bT2 + t) * DIN + kg * 4;
#pragma unroll
      for (int db = 0; db < 16; ++db) {
        us4v o;
#pragma unroll
        for (int rr = 0; rr < 4; ++rr) o[rr] = f2bf(acc_o[db][rr] * oinv);
        *(us4v*)(xp + db * 16) = o;
      }
    }
  } else {
    float* cp = Cur + ((size_t)b * T_ + t) * DD + kg * 4;
    float s1 = 0.f, s2 = 0.f;
#pragma unroll
    for (int db = 0; db < 16; ++db) {
      f32x4 c4 = *(const f32x4*)(cp + db * 16);
#pragma unroll
      for (int rr = 0; rr < 4; ++rr) {
        const float x = tanhf(acc_o[db][rr] * oinv) + c4[rr];
        acc_o[db][rr] = x;
        s1 += x;
        s2 += x * x;
      }
    }
    s1 += __shfl_xor(s1, 16, 64); s1 += __shfl_xor(s1, 32, 64);
    s2 += __shfl_xor(s2, 16, 64); s2 += __shfl_xor(s2, 32, 64);
    const float mean = s1 * (1.0f / 256.0f);
    const float var = s2 * (1.0f / 256.0f) - mean * mean;
    const float rinv = rsqrtf(var + LNEPS);
    ushort_t* xp = Xh + (bT2 + T_ + t) * DIN + kg * 4;
    if (lastLayer) {
      float* op = out + ((size_t)b * T_ + t) * (DD * 4) + h * DD + kg * 4;
      const us4v zz = {0, 0, 0, 0};
      const f32x4 zf = {0.f, 0.f, 0.f, 0.f};
#pragma unroll
      for (int db = 0; db < 16; ++db) {
        f32x4 w4 = *(const f32x4*)&nw[db * 16 + kg * 4];
        f32x4 b4 = *(const f32x4*)&nb[db * 16 + kg * 4];
        f32x4 y;
#pragma unroll
        for (int rr = 0; rr < 4; ++rr) y[rr] = (acc_o[db][rr] - mean) * rinv * w4[rr] + b4[rr];
        *(f32x4*)(op + db * 16) = y;
        *(f32x4*)(cp + db * 16) = zf;
        *(us4v*)(xp + db * 16) = zz;
      }
    } else {
#pragma unroll
      for (int db = 0; db < 16; ++db) {
        f32x4 w4 = *(const f32x4*)&nw[db * 16 + kg * 4];
        f32x4 b4 = *(const f32x4*)&nb[db * 16 + kg * 4];
        f32x4 y;
        us4v yh;
#pragma unroll
        for (int rr = 0; rr < 4; ++rr) {
          y[rr] = (acc_o[db][rr] - mean) * rinv * w4[rr] + b4[rr];
          yh[rr] = f2bf(y[rr]);
        }
        *(f32x4*)(cp + db * 16) = y;
        *(us4v*)(xp + db * 16) = yh;
      }
    }
  }

  // ---------- row0 mean-V fold (tc<4; all single-seg) ----------
  if (tc < 4) {
    __syncthreads();
    float* red = (float*)(lds + 65536);
    const int col = tc * 64 + (tid & 63);
    const int q4 = tid >> 6;
    float s = 0.f;
    for (int tl = q4 * 16; tl < q4 * 16 + 16; ++tl) {
      const ushort_t* vp = VTt + ((size_t)(b * 64 + tl)) * 8192 + col * 32;
#pragma unroll
      for (int j = 0; j < 32; j += 8) {
        uint4 v = *(const uint4*)(vp + j);
        const uint_t vs[4] = {v.x, v.y, v.z, v.w};
#pragma unroll
        for (int q = 0; q < 4; ++q) {
          s += __uint_as_float(vs[q] << 16);
          s += __uint_as_float(vs[q] & 0xffff0000u);
        }
      }
    }
    red[q4 * 64 + (tid & 63)] = s;
    __syncthreads();
    if (tid < 64)
      Xh[bT2 * DIN + tc * 64 + tid] =
          f2bf((red[tid] + red[64 + tid] + red[128 + tid] + red[192 + tid]) * (1.0f / 2048.0f));
  }
}

// ---------- merge + epilogue for multi-seg chunks (tc>=7): grid 100 x 256 ----------
__global__ __launch_bounds__(256) void k_merge(float* __restrict__ Cur,
                                               ushort_t* __restrict__ Xh,
                                               float* __restrict__ out,
                                               const float* __restrict__ nw,
                                               const float* __restrict__ nb,
                                               const ushort_t* __restrict__ PartO,
                                               const float* __restrict__ PartML,
                                               int lastLayer, int h) {
  const int tid = threadIdx.x;
  const int bx = blockIdx.x;
  const int b = bx & 3;
  const int tc = 7 + (bx >> 2);
  const int nt = tc + 2;
  const int nseg = (nt + SEGL - 1) / SEGL;
  const int slot0 = (b * 32 + tc) * 5;

  const int w = tid >> 6, lane = tid & 63;
  const int kg = lane >> 4, lr = lane & 15;
  const int half = w >> 1;
  const int tq = (w & 1) * 16 + lr;
  const int t = tc * 32 + tq;
  const int row = half * 32 + tq;
  const size_t bT2 = (size_t)b * T2;
  const f32x4 z4 = {0.f, 0.f, 0.f, 0.f};

  float mstar = -1e30f;
  for (int s = 0; s < nseg; ++s)
    mstar = fmaxf(mstar, PartML[(slot0 + s) * 128 + row]);
  float l_run = 0.f;
  f32x4 acc_o[16];
#pragma unroll
  for (int db = 0; db < 16; ++db) acc_o[db] = z4;
  for (int s = 0; s < nseg; ++s) {
    const float* pml = PartML + (slot0 + s) * 128;
    const float f = __expf(pml[row] - mstar);
    l_run += f * pml[64 + row];
    const ushort_t* po = PartO + ((size_t)(slot0 + s)) * (64 * 256) + row * 256 + kg * 4;
#pragma unroll
    for (int db = 0; db < 16; ++db) {
      us4v v4 = *(const us4v*)(po + db * 16);
#pragma unroll
      for (int q = 0; q < 4; ++q) acc_o[db][q] += f * bf2f(v4[q]);
    }
  }

  const float oinv = 1.0f / l_run;

  if (!half) {
    ushort_t* xp = Xh + (bT2 + t) * DIN + kg * 4;
#pragma unroll
    for (int db = 0; db < 16; ++db) {
      us4v o;
#pragma unroll
      for (int rr = 0; rr < 4; ++rr) o[rr] = f2bf(acc_o[db][rr] * oinv);
      *(us4v*)(xp + db * 16) = o;
    }
  } else {
    float* cp = Cur + ((size_t)b * T_ + t) * DD + kg * 4;
    float s1 = 0.f, s2 = 0.f;
#pragma unroll
    for (int db = 0; db < 16; ++db) {
      f32x4 c4 = *(const f32x4*)(cp + db * 16);
#pragma unroll
      for (int rr = 0; rr < 4; ++rr) {
        const float x = tanhf(acc_o[db][rr] * oinv) + c4[rr];
        acc_o[db][rr] = x;
        s1 += x;
        s2 += x * x;
      }
    }
    s1 += __shfl_xor(s1, 16, 64); s1 += __shfl_xor(s1, 32, 64);
    s2 += __shfl_xor(s2, 16, 64); s2 += __shfl_xor(s2, 32, 64);
    const float mean = s1 * (1.0f / 256.0f);
    const float var = s2 * (1.0f / 256.0f) - mean * mean;
    const float rinv = rsqrtf(var + LNEPS);
    ushort_t* xp = Xh + (bT2 + T_ + t) * DIN + kg * 4;
    if (lastLayer) {
      float* op = out + ((size_t)b * T_ + t) * (DD * 4) + h * DD + kg * 4;
      const us4v zz = {0, 0, 0, 0};
      const f32x4 zf = {0.f, 0.f, 0.f, 0.f};
#pragma unroll
      for (int db = 0; db < 16; ++db) {
        f32x4 w4 = *(const f32x4*)&nw[db * 16 + kg * 4];
        f32x4 b4 = *(const f32x4*)&nb[db * 16 + kg * 4];
        f32x4 y;
#pragma unroll
        for (int rr = 0; rr < 4; ++rr) y[rr] = (acc_o[db][rr] - mean) * rinv * w4[rr] + b4[rr];
        *(f32x4*)(op + db * 16) = y;
        *(f32x4*)(cp + db * 16) = zf;
        *(us4v*)(xp + db * 16) = zz;
      }
    } else {
#pragma unroll
      for (int db = 0; db < 16; ++db) {
        f32x4 w4 = *(const f32x4*)&nw[db * 16 + kg * 4];
        f32x4 b4 = *(const f32x4*)&nb[db * 16 + kg * 4];
        f32x4 y;
        us4v yh;
#pragma unroll
        for (int rr = 0; rr < 4; ++rr) {
          y[rr] = (acc_o[db][rr] - mean) * rinv * w4[rr] + b4[rr];
          yh[rr] = f2bf(y[rr]);
        }
        *(f32x4*)(cp + db * 16) = y;
        *(us4v*)(xp + db * 16) = yh;
      }
    }
  }
}

extern "C" void kernel_launch(void* const* d_in, const int* in_sizes, int n_in,
                              void* d_out, int out_size, void* d_ws, size_t ws_size,
                              hipStream_t stream) {
  const float* ev = (const float*)d_in[0];
  const float* tm = (const float*)d_in[1];
  const float* Wt = (const float*)d_in[3];
  const float* bt = (const float*)d_in[4];
  const float* Wq = (const float*)d_in[5];
  const float* bq = (const float*)d_in[6];
  const float* Wk = (const float*)d_in[7];
  const float* bk = (const float*)d_in[8];
  const float* Wv = (const float*)d_in[9];
  const float* bv = (const float*)d_in[10];
  const float* nw = (const float*)d_in[11];
  const float* nb = (const float*)d_in[12];
  float* out = (float*)d_out;

  char* p = (char*)d_ws;
  ushort_t* Xh  = (ushort_t*)p; p += (size_t)BB * T2 * DIN * 2;   // 8.39 MB
  ushort_t* Qh  = (ushort_t*)p; p += (size_t)BB * T2 * DD * 2;    // 4.19 MB
  ushort_t* Kh  = (ushort_t*)p; p += (size_t)BB * T2 * DD * 2;
  ushort_t* VTt = (ushort_t*)p; p += (size_t)BB * T2 * DD * 2;    // pi32-tiled V
  float* Cur    = (float*)p;    p += (size_t)BB * T_ * DD * 4;    // 4.19 MB
  ushort_t* WT  = (ushort_t*)p; p += (size_t)36 * DD * DIN * 2;   // 9.44 MB
  ushort_t* PartO = (ushort_t*)p; p += (size_t)640 * 64 * 256 * 2; // 21.0 MB
  float* PartML = (float*)p;                                       // 0.33 MB

  k_init<<<BB * T_, 256, 0, stream>>>(ev, tm, Wt, bt, Xh, Cur);
  k_transW<<<dim3(36, 32), 256, 0, stream>>>(Wq, Wk, Wv, WT);

  for (int h = 0; h < 4; ++h) {
    for (int l = 0; l < 3; ++l) {
      const int hl = h * 3 + l;
      k_qkv<<<dim3(128, 2, 3), 256, 0, stream>>>(Xh, WT, bq, bk, bv, Qh, Kh, VTt, hl,
                                                 (l == 0) ? 1 : 0);
      k_fpart<<<640, 256, 0, stream>>>(Qh, Kh, VTt, Cur, Xh, out, nw, nb,
                                       PartO, PartML, (l == 2) ? 1 : 0, h);
      k_merge<<<100, 256, 0, stream>>>(Cur, Xh, out, nw, nb,
                                       PartO, PartML, (l == 2) ? 1 : 0, h);
    }
  }
}